// Round 13
// baseline (463.188 us; speedup 1.0000x reference)
//
#include <hip/hip_runtime.h>
#include <math.h>

#define H 512
#define S 65
#define SP 80               // padded s-dimension (rows 65..79 zero/garbage)
#define HS (H * S)          // 33280
#define PHS (H * SP)        // 40960
#define KS3 24
#define KS4 16
#define GRID 256            // blocks of 512 thr; 1 block/CU (8 waves) resident
#define NSLOT 11            // 11 data barriers

// Round 12: all tasks restructured to 512-thread cooperative form (1 task
// per block, uniform syncs). Doubles waves/CU (4 -> 8) to hide latency.
// Coherence = round 11 (validated): sc1 write-through stores for
// intermediates, plain cached loads, flushless fabric-atomic barriers.
// Per-output-element FP order identical to the verified kernel.
//
// Workspace layout (all buffers WRITE-ONCE per run):
//  y: PHS  kqvp: 18*PHS  att1: 3*PHS  att2: PHS  plin1: 6*PHS  plin2: 6*PHS
//  kqvp2: 6*PHS  kqvp3: 6*PHS  y2: PHS  tpart: 24*1024  upart: 16*512
//  bar: NSLOT * 9 * 32 u32 (zeroed by captured memset)

// ---------------------------------------------------------------------------
// sc1 write-through store helpers (relaxed agent atomics)
// ---------------------------------------------------------------------------
__device__ __forceinline__ void st1cv(float* p, float v) {
    union { unsigned u; float f; } c; c.f = v;
    __hip_atomic_store((unsigned*)p, c.u, __ATOMIC_RELAXED,
                       __HIP_MEMORY_SCOPE_AGENT);
}
__device__ __forceinline__ void st2cv(float* p, float x, float y) {
    union { unsigned long long u; float2 f; } c; c.f = make_float2(x, y);
    __hip_atomic_store((unsigned long long*)p, c.u, __ATOMIC_RELAXED,
                       __HIP_MEMORY_SCOPE_AGENT);
}
__device__ __forceinline__ void st4cv(float* p, float4 v) {
    st2cv(p, v.x, v.y);
    st2cv(p + 2, v.z, v.w);
}

// ---------------------------------------------------------------------------
// Flushless global barrier (validated): vmcnt drain + relaxed fabric atomics.
// ---------------------------------------------------------------------------
__device__ __forceinline__ void gbar(unsigned* bar, int phase, int bid) {
    __syncthreads();
    if (threadIdx.x == 0) {
        unsigned* base   = bar + (size_t)phase * 9 * 32;
        unsigned* sub    = base + (bid & 7) * 32;
        unsigned* master = base + 8 * 32;
        asm volatile("s_waitcnt vmcnt(0)" ::: "memory");
        unsigned old = __hip_atomic_fetch_add(sub, 1u, __ATOMIC_RELAXED,
                                              __HIP_MEMORY_SCOPE_AGENT);
        if (old == (GRID / 8 - 1))
            __hip_atomic_fetch_add(master, 1u, __ATOMIC_RELAXED,
                                   __HIP_MEMORY_SCOPE_AGENT);
        while (__hip_atomic_load(master, __ATOMIC_RELAXED,
                                 __HIP_MEMORY_SCOPE_AGENT) < 8u)
            __builtin_amdgcn_s_sleep(16);
        asm volatile("" ::: "memory");
    }
    __syncthreads();
}

// ---------------------------------------------------------------------------
__device__ __forceinline__ void mac4(float4& c, float ax, float ay, float az,
                                     float aw, const float4& w0, const float4& w1,
                                     const float4& w2, const float4& w3) {
    c.x = fmaf(ax, w0.x, c.x); c.y = fmaf(ax, w0.y, c.y);
    c.z = fmaf(ax, w0.z, c.z); c.w = fmaf(ax, w0.w, c.w);
    c.x = fmaf(ay, w1.x, c.x); c.y = fmaf(ay, w1.y, c.y);
    c.z = fmaf(ay, w1.z, c.z); c.w = fmaf(ay, w1.w, c.w);
    c.x = fmaf(az, w2.x, c.x); c.y = fmaf(az, w2.y, c.y);
    c.z = fmaf(az, w2.z, c.z); c.w = fmaf(az, w2.w, c.w);
    c.x = fmaf(aw, w3.x, c.x); c.y = fmaf(aw, w3.y, c.y);
    c.z = fmaf(aw, w3.z, c.z); c.w = fmaf(aw, w3.w, c.w);
}

// ---------------------------------------------------------------------------
// KQV GEMM task, 512-thread: g = t>>3 covers rows 0..63 (acc0) and rows
// 64..79 for g<16 (accB). Same per-element k-order as the verified kernel.
// smem: Wt [0..2047], As [2048..7487] stride 68.
// ---------------------------------------------------------------------------
__device__ __forceinline__ void kqv_task(const float* __restrict__ wq,
                                         const float* __restrict__ wk,
                                         const float* __restrict__ wv,
                                         int mat0,
                                         const float* __restrict__ yT,
                                         float* __restrict__ part,
                                         int task, int t,
                                         float* __restrict__ smem) {
    int slot  = task / 96;
    int r96   = task - slot * 96;
    int which = r96 >> 5;
    int xx    = r96 & 31;
    int mat   = mat0 + slot;
    const float* W = (which == 0 ? wk : (which == 1 ? wq : wv)) + (size_t)mat * H * H;

    int n0   = (xx & 15) * 32;
    int kidx = xx >> 4;

    float* Wt = smem;
    float* As = smem + 2048;

    int nq = t & 7;
    int g  = t >> 3;            // 0..63
    bool rB = (g < 16);

    float4 acc0 = {0,0,0,0}, accB = {0,0,0,0};

    for (int ch = 0; ch < 4; ++ch) {
        int kc0 = kidx * 256 + ch * 64;
        {   // W stage: 512 float4 units, one per thread
            int wn  = t >> 4;
            int kf4 = t & 15;
            float4 w4 = *(const float4*)(W + (size_t)(n0 + wn) * H + kc0 + 4 * kf4);
            int sw = ((wn >> 2) ^ (kf4 & 7));
            int base = (4 * kf4) * 32 + 4 * sw + (wn & 3);
            Wt[base     ] = w4.x;
            Wt[base + 32] = w4.y;
            Wt[base + 64] = w4.z;
            Wt[base + 96] = w4.w;
        }
#pragma unroll
        for (int c = 0; c < 2; ++c) {   // As stage: 1280 float4 units
            int f = c * 512 + t;
            int as  = f >> 4;
            int kf4 = f & 15;
            *(float4*)(&As[as * 68 + 4 * kf4]) =
                *(const float4*)(yT + (size_t)as * H + kc0 + 4 * kf4);
        }
        if (t < 256) {
            int f = 1024 + t;
            int as  = f >> 4;
            int kf4 = f & 15;
            *(float4*)(&As[as * 68 + 4 * kf4]) =
                *(const float4*)(yT + (size_t)as * H + kc0 + 4 * kf4);
        }
        __syncthreads();

#pragma unroll
        for (int k4 = 0; k4 < 16; ++k4) {
            int swc = 4 * (nq ^ (k4 & 7));
            float4 w0 = *(const float4*)(&Wt[(4 * k4 + 0) * 32 + swc]);
            float4 w1 = *(const float4*)(&Wt[(4 * k4 + 1) * 32 + swc]);
            float4 w2 = *(const float4*)(&Wt[(4 * k4 + 2) * 32 + swc]);
            float4 w3 = *(const float4*)(&Wt[(4 * k4 + 3) * 32 + swc]);
            {
                float4 a = *(const float4*)(&As[g * 68 + 4 * k4]);
                mac4(acc0, a.x, a.y, a.z, a.w, w0, w1, w2, w3);
            }
            if (rB) {
                float4 a = *(const float4*)(&As[(g + 64) * 68 + 4 * k4]);
                mac4(accB, a.x, a.y, a.z, a.w, w0, w1, w2, w3);
            }
        }
        __syncthreads();
    }

    float* P = part + (size_t)((slot * 3 + which) * 2 + kidx) * PHS;
    st4cv(P + (size_t)g * H + n0 + 4 * nq, acc0);
    if (rB) st4cv(P + (size_t)(g + 64) * H + n0 + 4 * nq, accB);
}

// ---------------------------------------------------------------------------
// Layer-1 KQV, 512-thread, embed fused: As[s][k] = emb[k*S+s]*x[s].
// ---------------------------------------------------------------------------
__device__ __forceinline__ void kqv1_task(const float* __restrict__ wq,
                                          const float* __restrict__ wk,
                                          const float* __restrict__ wv,
                                          const float* __restrict__ emb,
                                          float* __restrict__ part,
                                          int task, int t,
                                          float* __restrict__ smem,
                                          const float* __restrict__ xv) {
    int slot  = task / 96;
    int r96   = task - slot * 96;
    int which = r96 >> 5;
    int xx    = r96 & 31;
    const float* W = (which == 0 ? wk : (which == 1 ? wq : wv)) + (size_t)slot * H * H;

    int n0   = (xx & 15) * 32;
    int kidx = xx >> 4;

    float* Wt = smem;
    float* As = smem + 2048;

    int nq = t & 7;
    int g  = t >> 3;
    bool rB = (g < 16);

    float4 acc0 = {0,0,0,0}, accB = {0,0,0,0};

    for (int ch = 0; ch < 4; ++ch) {
        int kc0 = kidx * 256 + ch * 64;
        {
            int wn  = t >> 4;
            int kf4 = t & 15;
            float4 w4 = *(const float4*)(W + (size_t)(n0 + wn) * H + kc0 + 4 * kf4);
            int sw = ((wn >> 2) ^ (kf4 & 7));
            int base = (4 * kf4) * 32 + 4 * sw + (wn & 3);
            Wt[base     ] = w4.x;
            Wt[base + 32] = w4.y;
            Wt[base + 64] = w4.z;
            Wt[base + 96] = w4.w;
        }
#pragma unroll
        for (int c = 0; c < 2; ++c) {
            int f = c * 512 + t;
            int as  = (f & 15) + 16 * (f >> 8);   // 0..79
            int kf4 = (f >> 4) & 15;
            int k0 = kc0 + 4 * kf4;
            float xs = xv[as];
            float4 v;
            v.x = emb[(size_t)(k0 + 0) * S + as] * xs;
            v.y = emb[(size_t)(k0 + 1) * S + as] * xs;
            v.z = emb[(size_t)(k0 + 2) * S + as] * xs;
            v.w = emb[(size_t)(k0 + 3) * S + as] * xs;
            *(float4*)(&As[as * 68 + 4 * kf4]) = v;
        }
        if (t < 256) {
            int f = 1024 + t;
            int as  = (f & 15) + 16 * (f >> 8);
            int kf4 = (f >> 4) & 15;
            int k0 = kc0 + 4 * kf4;
            float xs = xv[as];
            float4 v;
            v.x = emb[(size_t)(k0 + 0) * S + as] * xs;
            v.y = emb[(size_t)(k0 + 1) * S + as] * xs;
            v.z = emb[(size_t)(k0 + 2) * S + as] * xs;
            v.w = emb[(size_t)(k0 + 3) * S + as] * xs;
            *(float4*)(&As[as * 68 + 4 * kf4]) = v;
        }
        __syncthreads();

#pragma unroll
        for (int k4 = 0; k4 < 16; ++k4) {
            int swc = 4 * (nq ^ (k4 & 7));
            float4 w0 = *(const float4*)(&Wt[(4 * k4 + 0) * 32 + swc]);
            float4 w1 = *(const float4*)(&Wt[(4 * k4 + 1) * 32 + swc]);
            float4 w2 = *(const float4*)(&Wt[(4 * k4 + 2) * 32 + swc]);
            float4 w3 = *(const float4*)(&Wt[(4 * k4 + 3) * 32 + swc]);
            {
                float4 a = *(const float4*)(&As[g * 68 + 4 * k4]);
                mac4(acc0, a.x, a.y, a.z, a.w, w0, w1, w2, w3);
            }
            if (rB) {
                float4 a = *(const float4*)(&As[(g + 64) * 68 + 4 * k4]);
                mac4(accB, a.x, a.y, a.z, a.w, w0, w1, w2, w3);
            }
        }
        __syncthreads();
    }

    float* P = part + (size_t)((slot * 3 + which) * 2 + kidx) * PHS;
    st4cv(P + (size_t)g * H + n0 + 4 * nq, acc0);
    if (rB) st4cv(P + (size_t)(g + 64) * H + n0 + 4 * nq, accB);
}

// ---------------------------------------------------------------------------
__device__ __forceinline__ float score_part(const float* __restrict__ Q0,
                                            const float* __restrict__ Q1,
                                            const float* __restrict__ ka,
                                            int b, int t) {
    const float4* q0 = (const float4*)(Q0 + (size_t)b * H) + t * 32;
    const float4* q1 = (const float4*)(Q1 + (size_t)b * H) + t * 32;
    const float4* kl = (const float4*)ka + t * 32;
    float4 c0 = {0,0,0,0}, c1 = {0,0,0,0};
#pragma unroll
    for (int u = 0; u < 32; u += 2) {
        float4 qa = q0[u], qb = q1[u], k0 = kl[u];
        float4 qc = q0[u+1], qd = q1[u+1], k1 = kl[u+1];
        c0.x = fmaf(k0.x, qa.x + qb.x, c0.x);
        c0.y = fmaf(k0.y, qa.y + qb.y, c0.y);
        c0.z = fmaf(k0.z, qa.z + qb.z, c0.z);
        c0.w = fmaf(k0.w, qa.w + qb.w, c0.w);
        c1.x = fmaf(k1.x, qc.x + qd.x, c1.x);
        c1.y = fmaf(k1.y, qc.y + qd.y, c1.y);
        c1.z = fmaf(k1.z, qc.z + qd.z, c1.z);
        c1.w = fmaf(k1.w, qc.w + qd.w, c1.w);
    }
    return ((c0.x + c0.y) + (c0.z + c0.w)) + ((c1.x + c1.y) + (c1.z + c1.w));
}

// ---------------------------------------------------------------------------
// Attention task, 512-thread. Score split kept at the verified 4-way (on
// tid<256); V-accum is one hh per thread. Same FP order per element.
// smem: ka[512] sp[260] smv[65] p[65].
// ---------------------------------------------------------------------------
__device__ __forceinline__ void attn_task(const float* __restrict__ base,
                                          float* __restrict__ ao,
                                          int a, int tid,
                                          float* __restrict__ smem) {
    const float* K0 = base;
    const float* K1 = base + PHS;
    const float* Q0 = base + 2 * (size_t)PHS;
    const float* Q1 = base + 3 * (size_t)PHS;
    const float* V0 = base + 4 * (size_t)PHS;
    const float* V1 = base + 5 * (size_t)PHS;

    float* ka  = smem;          // 512
    float* sp  = smem + 512;    // 4*65
    float* smv = smem + 772;    // 65
    float* p   = smem + 837;    // 65

    ka[tid] = K0[(size_t)a * H + tid] + K1[(size_t)a * H + tid];
    __syncthreads();

    if (tid < 256) {
        int b = tid & 63;
        int tq = tid >> 6;
        sp[tq * 65 + b] = score_part(Q0, Q1, ka, b, tq);
    }
    if (tid < 4) sp[tid * 65 + 64] = score_part(Q0, Q1, ka, 64, tid);
    __syncthreads();

    if (tid < S) {
        smv[tid] = (sp[tid] + sp[65 + tid]) + (sp[130 + tid] + sp[195 + tid]);
    }
    __syncthreads();

    float maxv = -INFINITY;
    for (int i = 0; i < S; ++i) maxv = fmaxf(maxv, smv[i]);
    float sum = 0.0f;
    for (int i = 0; i < S; ++i) sum += expf(smv[i] - maxv);
    float inv = 1.0f / sum;
    if (tid < S) p[tid] = expf(smv[tid] - maxv) * inv;
    __syncthreads();

    {
        int hh = tid;
        float a0 = 0.f, a1 = 0.f;
#pragma unroll 4
        for (int b = 0; b < 64; b += 2) {
            a0 = fmaf(p[b    ], V0[(size_t)(b    ) * H + hh] + V1[(size_t)(b    ) * H + hh], a0);
            a1 = fmaf(p[b + 1], V0[(size_t)(b + 1) * H + hh] + V1[(size_t)(b + 1) * H + hh], a1);
        }
        a0 = fmaf(p[64], V0[(size_t)64 * H + hh] + V1[(size_t)64 * H + hh], a0);
        st1cv(ao + hh, a0 + a1);
    }
    __syncthreads();
}

// ---------------------------------------------------------------------------
// 4-row linear block, 512-thread: row-chains split 2/2 across thread halves
// (each row's FP chain identical to the verified 256-thread version).
// smem: Ar [0..1023], red [1024..3071] (float4).
// ---------------------------------------------------------------------------
__device__ __forceinline__ void lin4row_dev(float* __restrict__ smem,
                                            const float* __restrict__ att,
                                            int col0,
                                            const float* __restrict__ L,
                                            float* __restrict__ dst,
                                            int s0, int tid) {
    float* Ar   = smem;                          // 4*256
    float4* red = (float4*)(smem + 1024);        // 4*128 float4

    if (tid < 256) {
        int rr = tid >> 6;
        int cc = tid & 63;
        *(float4*)(&Ar[rr * 256 + cc * 4]) =
            *(const float4*)(att + (size_t)(s0 + rr) * H + col0 + cc * 4);
    }
    __syncthreads();

    int tl   = tid & 255;
    int half = tid >> 8;            // 0: rows 0,1   1: rows 2,3
    int h4 = (tl & 127) * 4;
    int jh = tl >> 7;
    const float* Lj = L + (size_t)(jh * 128) * H + h4;
    const float* A0 = Ar + jh * 128 + half * 512;

    float4 cA = {0,0,0,0}, cB = {0,0,0,0};
#pragma unroll 8
    for (int j = 0; j < 128; ++j) {
        float4 L4 = *(const float4*)(Lj + (size_t)j * H);
        float aA = A0[j], aB = A0[256 + j];
        cA.x = fmaf(aA, L4.x, cA.x); cA.y = fmaf(aA, L4.y, cA.y);
        cA.z = fmaf(aA, L4.z, cA.z); cA.w = fmaf(aA, L4.w, cA.w);
        cB.x = fmaf(aB, L4.x, cB.x); cB.y = fmaf(aB, L4.y, cB.y);
        cB.z = fmaf(aB, L4.z, cB.z); cB.w = fmaf(aB, L4.w, cB.w);
    }

    if (jh == 1) {
        int x = tl & 127;
        red[half * 256 + x] = cA;
        red[half * 256 + 128 + x] = cB;
    }
    __syncthreads();
    if (jh == 0) {
        float4 rA = red[half * 256 + tl];
        float4 rB = red[half * 256 + 128 + tl];
        cA.x += rA.x; cA.y += rA.y; cA.z += rA.z; cA.w += rA.w;
        cB.x += rB.x; cB.y += rB.y; cB.z += rB.z; cB.w += rB.w;
        st4cv(dst + (size_t)(s0 + half * 2 + 0) * H + h4, cA);
        st4cv(dst + (size_t)(s0 + half * 2 + 1) * H + h4, cB);
    }
    __syncthreads();
}

// ---------------------------------------------------------------------------
// lin3 row-64 slices, 512-thread: 2 idx units per task (idx = idx2*2+half).
// ---------------------------------------------------------------------------
__device__ __forceinline__ void lin3_slice(const float* __restrict__ att1,
                                           const float* __restrict__ lin3,
                                           float* __restrict__ tpart,
                                           int idx2, int tid) {
    int idx = idx2 * 2 + (tid >> 8);      // 0..63
    int tt  = tid & 255;
    int j2 = (idx & 3) * 256 + tt;
    int ks = idx >> 2;                    // 0..15
    const float* row = att1 + (size_t)(ks >> 3) * PHS + (size_t)64 * H;
    int j0 = (ks & 7) * 64;
    int jbase = ks * 64;
    float a0 = 0.f, a1 = 0.f, a2 = 0.f, a3 = 0.f;
    for (int j = 0; j < 64; j += 4) {
        a0 = fmaf(row[j0 + j + 0], lin3[(size_t)(jbase + j + 0) * 1024 + j2], a0);
        a1 = fmaf(row[j0 + j + 1], lin3[(size_t)(jbase + j + 1) * 1024 + j2], a1);
        a2 = fmaf(row[j0 + j + 2], lin3[(size_t)(jbase + j + 2) * 1024 + j2], a2);
        a3 = fmaf(row[j0 + j + 3], lin3[(size_t)(jbase + j + 3) * 1024 + j2], a3);
    }
    st1cv(tpart + ks * 1024 + j2, (a0 + a1) + (a2 + a3));
}

// ---------------------------------------------------------------------------
__global__ void __launch_bounds__(512)
reversi_mega(const float* __restrict__ inputs, const float* __restrict__ emb,
             const float* __restrict__ wq, const float* __restrict__ wk,
             const float* __restrict__ wv, const float* __restrict__ lin1,
             const float* __restrict__ lin2, const float* __restrict__ lin3,
             const float* __restrict__ lin4, const float* __restrict__ lin5,
             float* __restrict__ out, float* __restrict__ ws) {
    __shared__ __align__(16) float smem[7568];   // 30272 B (union + xv[80])

    float* y     = ws;                  // unused
    float* kqvp  = y     + PHS;         // 18*PHS layer-1 kqv (P1)
    float* att1  = kqvp  + 18 * PHS;    // 3*PHS  (P2)
    float* att2  = att1  + 3 * PHS;     // PHS    (P6)
    float* plin1 = att2  + PHS;         // 6*PHS  (P3)
    float* plin2 = plin1 + 6 * PHS;     // 6*PHS  (P3 segs0-3, P7 segs4-5)
    float* kqvp2 = plin2 + 6 * PHS;     // 6*PHS  layer-2 kqv (P5)
    float* kqvp3 = kqvp2 + 6 * PHS;     // 6*PHS  layer-3 kqv (P9)
    float* y2    = kqvp3 + 6 * PHS;     // layer-2 output (P8 reads y; see P4)
    float* yy    = ws;                  // layer-1 output (P4) -> reuse y slot
    float* tpart = y2    + PHS;         // 24*1024
    float* upart = tpart + KS3 * 1024;  // 16*512
    unsigned* bar = (unsigned*)(upart + KS4 * 512);   // NSLOT*9*32 u32

    int tid  = threadIdx.x;             // 0..511
    int bid  = blockIdx.x;
    int nbk  = gridDim.x;
    int bi = 0;

    // ---- P1: layer-1 KQV (mats 0..2), embed fused, 288 tasks ----
    float* xv = smem + 7488;
    if (tid < 80) {
        float xvv = 0.f;
        if (tid < S) xvv = (tid == 64) ? 1.0f : inputs[tid];
        xv[tid] = xvv;
    }
    __syncthreads();
    for (int task = bid; task < 288; task += nbk)
        kqv1_task(wq, wk, wv, emb, kqvp, task, tid, smem, xv);
    gbar(bar, bi++, bid);

    // ---- P2: layer-1 attention, 195 tasks ----
    if (bid < 195) {
        int slot = bid / 65;
        int r = bid - slot * 65;
        attn_task(kqvp + (size_t)slot * 6 * PHS,
                  att1 + (size_t)slot * PHS + (size_t)r * H, r, tid, smem);
    }
    gbar(bar, bi++, bid);

    // ---- P3: mega_lin, 202 tasks (170 lin4row + 32 double-lin3) ----
    if (bid < 202) {
        if (bid < 102) {
            int seg = bid / 17, pp = bid % 17;
            lin4row_dev(smem, att1 + (size_t)(seg >> 1) * PHS,
                        (seg & 1) * 256, lin1 + (size_t)(seg * 256) * H,
                        plin1 + (size_t)seg * PHS, pp * 4, tid);
        } else if (bid < 170) {
            int u = bid - 102;
            int s2 = u / 17, pp = u % 17;
            lin4row_dev(smem, att1 + (size_t)(s2 >> 1) * PHS,
                        (s2 & 1) * 256, lin2 + (size_t)(s2 * 256) * H,
                        plin2 + (size_t)s2 * PHS, pp * 4, tid);
        } else {
            lin3_slice(att1, lin3, tpart, bid - 170, tid);
        }
    }
    gbar(bar, bi++, bid);

    // ---- P4: combine plin1 -> yy (relu); pad rows zeroed; 80 tasks ----
    for (int task = bid; task < 80; task += nbk) {
        int i = task * 512 + tid;
        if (i < HS) {
            float s = 0.f;
#pragma unroll
            for (int p = 0; p < 6; ++p) s += plin1[(size_t)p * PHS + i];
            st1cv(yy + i, fmaxf(s, 0.0f));
        } else {
            st1cv(yy + i, 0.f);
        }
    }
    gbar(bar, bi++, bid);

    // ---- P5: layer-2 KQV (mat 5) -> kqvp2, 96 tasks ----
    if (bid < 96)
        kqv_task(wq, wk, wv, 5, yy, kqvp2, bid, tid, smem);
    gbar(bar, bi++, bid);

    // ---- P6: layer-2 attention, 65 tasks ----
    if (bid < 65)
        attn_task(kqvp2, att2 + (size_t)bid * H, bid, tid, smem);
    gbar(bar, bi++, bid);

    // ---- P7: lin2 segs 4,5 from att2, 34 tasks ----
    if (bid < 34) {
        int seg = 4 + bid / 17, pp = bid % 17;
        lin4row_dev(smem, att2, (seg & 1) * 256, lin2 + (size_t)(seg * 256) * H,
                    plin2 + (size_t)seg * PHS, pp * 4, tid);
    }
    gbar(bar, bi++, bid);

    // ---- P8: combine plin2 -> y2 (relu); pads zeroed; 80 tasks ----
    for (int task = bid; task < 80; task += nbk) {
        int i = task * 512 + tid;
        if (i < HS) {
            float s = 0.f;
#pragma unroll
            for (int p = 0; p < 6; ++p) s += plin2[(size_t)p * PHS + i];
            st1cv(y2 + i, fmaxf(s, 0.0f));
        } else {
            st1cv(y2 + i, 0.f);
        }
    }
    gbar(bar, bi++, bid);

    // ---- P9: layer-3 KQV (mat 8) -> kqvp3, 96 tasks ----
    if (bid < 96)
        kqv_task(wq, wk, wv, 8, y2, kqvp3, bid, tid, smem);
    gbar(bar, bi++, bid);

    // ---- P10: layer-3 attention (row 64) + lin3 slices 16..23, 16 tasks ----
    if (bid < 16) {
        int ks = 16 + (bid >> 1);
        int xb = (bid & 1) * 2 + (tid >> 8);   // 0..3
        int tt = tid & 255;
        int j2 = xb * 256 + tt;
        int j0 = (ks & 7) * 64;

        const float* K0 = kqvp3;
        const float* K1 = kqvp3 + PHS;
        const float* Q0 = kqvp3 + 2 * (size_t)PHS;
        const float* Q1 = kqvp3 + 3 * (size_t)PHS;
        const float* V0 = kqvp3 + 4 * (size_t)PHS;
        const float* V1 = kqvp3 + 5 * (size_t)PHS;

        float* ka    = smem;          // 512
        float* sp    = smem + 512;    // 260
        float* smv   = smem + 772;    // 65
        float* p     = smem + 837;    // 65
        float* att_s = smem + 902;    // 64

        ka[tid] = K0[(size_t)64 * H + tid] + K1[(size_t)64 * H + tid];
        __syncthreads();

        if (tid < 256) {
            int b = tid & 63;
            int tq = tid >> 6;
            sp[tq * 65 + b] = score_part(Q0, Q1, ka, b, tq);
        }
        if (tid < 4) sp[tid * 65 + 64] = score_part(Q0, Q1, ka, 64, tid);
        __syncthreads();

        if (tid < S) {
            smv[tid] = (sp[tid] + sp[65 + tid]) + (sp[130 + tid] + sp[195 + tid]);
        }
        __syncthreads();

        float maxv = -INFINITY;
        for (int i = 0; i < S; ++i) maxv = fmaxf(maxv, smv[i]);
        float sum = 0.0f;
        for (int i = 0; i < S; ++i) sum += expf(smv[i] - maxv);
        float inv = 1.0f / sum;
        if (tid < S) p[tid] = expf(smv[tid] - maxv) * inv;
        __syncthreads();

        if (tid < 64) {
            int hh = j0 + tid;
            float a0 = 0.f, a1 = 0.f;
#pragma unroll 4
            for (int b = 0; b < 64; b += 2) {
                a0 = fmaf(p[b    ], V0[(size_t)(b    ) * H + hh] + V1[(size_t)(b    ) * H + hh], a0);
                a1 = fmaf(p[b + 1], V0[(size_t)(b + 1) * H + hh] + V1[(size_t)(b + 1) * H + hh], a1);
            }
            a0 = fmaf(p[64], V0[(size_t)64 * H + hh] + V1[(size_t)64 * H + hh], a0);
            att_s[tid] = a0 + a1;
        }
        __syncthreads();

        int jbase = ks * 64;
        float a0 = 0.f, a1 = 0.f, a2 = 0.f, a3 = 0.f;
        for (int j = 0; j < 64; j += 4) {
            a0 = fmaf(att_s[j + 0], lin3[(size_t)(jbase + j + 0) * 1024 + j2], a0);
            a1 = fmaf(att_s[j + 1], lin3[(size_t)(jbase + j + 1) * 1024 + j2], a1);
            a2 = fmaf(att_s[j + 2], lin3[(size_t)(jbase + j + 2) * 1024 + j2], a2);
            a3 = fmaf(att_s[j + 3], lin3[(size_t)(jbase + j + 3) * 1024 + j2], a3);
        }
        st1cv(tpart + ks * 1024 + j2, (a0 + a1) + (a2 + a3));
        __syncthreads();
    }
    gbar(bar, bi++, bid);

    // ---- P11: lin4 partials, 16 tasks (full 512-wide hh) ----
    if (bid < 16) {
        int ks = bid;
        float* tl = smem;             // 64
        int hh = tid;
        int j2base = ks * 64;

        if (tid < 64) {
            int j2 = j2base + tid;
            float s = 0.f;
#pragma unroll
            for (int p = 0; p < KS3; ++p) s += tpart[p * 1024 + j2];
            tl[tid] = fmaxf(s, 0.f);
        }
        __syncthreads();

        float a0 = 0.f, a1 = 0.f, a2 = 0.f, a3 = 0.f;
        for (int j = 0; j < 64; j += 4) {
            a0 = fmaf(tl[j + 0], lin4[(size_t)(j2base + j + 0) * H + hh], a0);
            a1 = fmaf(tl[j + 1], lin4[(size_t)(j2base + j + 1) * H + hh], a1);
            a2 = fmaf(tl[j + 2], lin4[(size_t)(j2base + j + 2) * H + hh], a2);
            a3 = fmaf(tl[j + 3], lin4[(size_t)(j2base + j + 3) * H + hh], a3);
        }
        st1cv(upart + ks * H + hh, (a0 + a1) + (a2 + a3));
        __syncthreads();
    }
    gbar(bar, bi++, bid);

    // ---- P12: tanh + lin5 -> out (block 0; original 512-thread form) ----
    if (bid == 0) {
        float* u  = smem;             // 512
        float* pr = smem + 512;       // 8*64

        {
            float s = 0.f;
#pragma unroll
            for (int p = 0; p < KS4; ++p) s += upart[p * H + tid];
            u[tid] = tanhf(s);
        }
        __syncthreads();

        int o  = tid & 63;
        int sl = tid >> 6;            // 0..7
        float acc = 0.f;
        int h0 = sl * 64;
#pragma unroll 8
        for (int j = 0; j < 64; ++j) {
            acc = fmaf(u[h0 + j], lin5[(h0 + j) * 64 + o], acc);
        }
        pr[sl * 64 + o] = acc;
        __syncthreads();

        if (tid < 64) {
            float s = 0.f;
#pragma unroll
            for (int p = 0; p < 8; ++p) s += pr[p * 64 + tid];
            out[tid] = s;
        }
    }
}

// ---------------------------------------------------------------------------
extern "C" void kernel_launch(void* const* d_in, const int* in_sizes, int n_in,
                              void* d_out, int out_size, void* d_ws, size_t ws_size,
                              hipStream_t stream) {
    const float* inputs  = (const float*)d_in[0];
    const float* emb     = (const float*)d_in[1];
    const float* wq      = (const float*)d_in[2];
    const float* wk      = (const float*)d_in[3];
    const float* wv      = (const float*)d_in[4];
    const float* linear1 = (const float*)d_in[5];
    const float* linear2 = (const float*)d_in[6];
    const float* linear3 = (const float*)d_in[7];
    const float* linear4 = (const float*)d_in[8];
    const float* linear5 = (const float*)d_in[9];
    float* out = (float*)d_out;
    float* ws  = (float*)d_ws;

    // Barrier region after all live data: 48*PHS + 24*1024 + 16*512 floats.
    size_t bar_off_floats = (size_t)48 * PHS + KS3 * 1024 + KS4 * 512;
    void* bar_ptr = (void*)(ws + bar_off_floats);
    hipMemsetAsync(bar_ptr, 0, NSLOT * 9 * 32 * sizeof(unsigned), stream);

    reversi_mega<<<dim3(GRID), dim3(512), 0, stream>>>(
        inputs, emb, wq, wk, wv, linear1, linear2, linear3, linear4, linear5,
        out, ws);
}